// Round 1
// baseline (2708.971 us; speedup 1.0000x reference)
//
#include <hip/hip_runtime.h>

#define SL 2048
#define BS 4
#define DM 512
#define NH 8
#define DH 64
#define RD 8192      // SL*BS rows
#define DF 2048      // 4*DM

#define BM 128
#define BN 128
#define BK 32

typedef unsigned short u16;
typedef __attribute__((ext_vector_type(8))) short short8;
typedef __attribute__((ext_vector_type(4))) float f32x4;

// ---------------- helpers ----------------
__device__ __forceinline__ float bf2f(u16 u) {
  return __uint_as_float(((unsigned)u) << 16);
}
__device__ __forceinline__ u16 f2bf(float f) {
  unsigned u = __float_as_uint(f);
  unsigned r = (u + 0x7fffu + ((u >> 16) & 1u)) >> 16;  // RNE
  return (u16)r;
}

typedef __attribute__((address_space(3))) unsigned int lds_u32;
typedef __attribute__((address_space(1))) unsigned int gbl_u32;
__device__ __forceinline__ void gload_lds16(const void* g, void* l) {
  __builtin_amdgcn_global_load_lds((gbl_u32*)g, (lds_u32*)l, 16, 0, 0);
}

// ---------------- descriptors ----------------
struct GemmDesc {
  const u16* A;      // M x K row-major bf16
  const u16* B;      // N x K row-major bf16 (B^T layout)
  const float* bias; // len N (may be null)
  const float* res;  // M x N fp32 residual (may be null)
  u16* Cb;           // bf16 out (null -> fp32 out)
  float* Cf;         // fp32 out
  float bmul;        // bias multiplier
  int relu;
};
struct GemmBatch { GemmDesc d[9]; };

struct LnDesc { const float* x; const float* g; const float* b; u16* yb; float* yf; };
struct LnBatch { LnDesc d[6]; };

struct AttnDesc { const u16* Q; const u16* K; const u16* V; u16* O; };
struct AttnBatch { AttnDesc d[3]; };

struct CvtDesc { const float* src; u16* dst; int n8; float scale; };
struct CvtBatch { CvtDesc d[6]; };

struct EmbBatch { const float* src[3]; float* dst[3]; const float* pos; };
struct AddBatch { const float* a[3]; const float* b[3]; float* o[3]; };

// ---------------- GEMM (m97 structure: 128x128 tile, BK=32, 4 waves) ----------------
__global__ __launch_bounds__(256) void gemm_k(GemmBatch args, int M, int N, int K) {
  GemmDesc g = args.d[blockIdx.z];
  __shared__ u16 As[BM * BK];
  __shared__ u16 Ws[BN * BK];
  const int t = threadIdx.x;
  const int w = t >> 6, l = t & 63;
  const int mb = blockIdx.y, nb = blockIdx.x;
  const u16* Ag = g.A + (size_t)mb * BM * K;
  const u16* Wg = g.B + (size_t)nb * BN * K;
  f32x4 acc[4][4];
#pragma unroll
  for (int m = 0; m < 4; ++m)
#pragma unroll
    for (int n = 0; n < 4; ++n) acc[m][n] = f32x4{0.f, 0.f, 0.f, 0.f};
  const int wr = (w >> 1) * 64, wc = (w & 1) * 64;
  const int lr = l & 15, lk = (l >> 4) * 8;

  for (int k0 = 0; k0 < K; k0 += BK) {
    if (k0) __syncthreads();
#pragma unroll
    for (int i = 0; i < 2; ++i) {
      const int u = (i << 8) + t;           // staging unit: 16B each
      const int row = u >> 2, col = (u & 3) << 3;
      gload_lds16(Ag + (size_t)row * K + k0 + col, (char*)As + (i << 12) + (w << 10));
      gload_lds16(Wg + (size_t)row * K + k0 + col, (char*)Ws + (i << 12) + (w << 10));
    }
    __syncthreads();  // compiler drains vmcnt(0) before barrier
    short8 af[4], bfr[4];
#pragma unroll
    for (int m = 0; m < 4; ++m)
      af[m] = *(const short8*)(As + (wr + m * 16 + lr) * BK + lk);
#pragma unroll
    for (int n = 0; n < 4; ++n)
      bfr[n] = *(const short8*)(Ws + (wc + n * 16 + lr) * BK + lk);
#pragma unroll
    for (int m = 0; m < 4; ++m)
#pragma unroll
      for (int n = 0; n < 4; ++n)
        acc[m][n] = __builtin_amdgcn_mfma_f32_16x16x32_bf16(af[m], bfr[n], acc[m][n], 0, 0, 0);
  }

  const int c0 = nb * BN + wc + lr;
  const int r0 = mb * BM + wr + (l >> 4) * 4;
#pragma unroll
  for (int n = 0; n < 4; ++n) {
    const int gc = c0 + n * 16;
    const float bi = g.bias ? g.bias[gc] * g.bmul : 0.f;
#pragma unroll
    for (int m = 0; m < 4; ++m) {
#pragma unroll
      for (int r = 0; r < 4; ++r) {
        const size_t off = (size_t)(r0 + m * 16 + r) * N + gc;
        float v = acc[m][n][r] + bi;
        if (g.res) v += g.res[off];
        if (g.relu) v = fmaxf(v, 0.f);
        if (g.Cb) g.Cb[off] = f2bf(v);
        else g.Cf[off] = v;
      }
    }
  }
}

// ---------------- LayerNorm: wave-per-row, D=512, 8 floats/lane ----------------
__global__ __launch_bounds__(256) void ln_k(LnBatch args) {
  LnDesc d = args.d[blockIdx.y];
  const int row = blockIdx.x * 4 + (threadIdx.x >> 6);
  const int l = threadIdx.x & 63;
  const float* xp = d.x + (size_t)row * DM + l * 8;
  float4 x0 = *(const float4*)xp;
  float4 x1 = *(const float4*)(xp + 4);
  float xv[8] = {x0.x, x0.y, x0.z, x0.w, x1.x, x1.y, x1.z, x1.w};
  float s = 0.f, ss = 0.f;
#pragma unroll
  for (int j = 0; j < 8; ++j) { s += xv[j]; ss += xv[j] * xv[j]; }
#pragma unroll
  for (int m = 1; m < 64; m <<= 1) {
    s += __shfl_xor(s, m, 64);
    ss += __shfl_xor(ss, m, 64);
  }
  const float mean = s * (1.f / DM);
  const float var = ss * (1.f / DM) - mean * mean;
  const float rstd = rsqrtf(var + 1e-5f);
  float4 g0 = *(const float4*)(d.g + l * 8);
  float4 g1 = *(const float4*)(d.g + l * 8 + 4);
  float4 b0 = *(const float4*)(d.b + l * 8);
  float4 b1 = *(const float4*)(d.b + l * 8 + 4);
  float gv[8] = {g0.x, g0.y, g0.z, g0.w, g1.x, g1.y, g1.z, g1.w};
  float bv[8] = {b0.x, b0.y, b0.z, b0.w, b1.x, b1.y, b1.z, b1.w};
  float y[8];
#pragma unroll
  for (int j = 0; j < 8; ++j) y[j] = (xv[j] - mean) * rstd * gv[j] + bv[j];
  if (d.yb) {
    short8 p;
#pragma unroll
    for (int j = 0; j < 8; ++j) p[j] = (short)f2bf(y[j]);
    *(short8*)(d.yb + (size_t)row * DM + l * 8) = p;
  } else {
    float* o = d.yf + (size_t)row * DM + l * 8;
    *(float4*)o = float4{y[0], y[1], y[2], y[3]};
    *(float4*)(o + 4) = float4{y[4], y[5], y[6], y[7]};
  }
}

// ---------------- windowed attention (PF=3, positions s-2,s-1,s mod SL) ----------------
__global__ __launch_bounds__(256) void attn_k(AttnBatch args) {
  AttnDesc d = args.d[blockIdx.y];
  const int idx = blockIdx.x * 256 + threadIdx.x;  // (s,b,h), 65536 total
  const int h = idx & 7;
  const int b = (idx >> 3) & 3;
  const int s = idx >> 5;
  const int s0 = (s + SL - 2) & (SL - 1);
  const int s1 = (s + SL - 1) & (SL - 1);
  const size_t rq = (size_t)(s * BS + b) * DM + h * DH;
  const size_t r0 = (size_t)(s0 * BS + b) * DM + h * DH;
  const size_t r1 = (size_t)(s1 * BS + b) * DM + h * DH;
  float d0 = 0.f, d1 = 0.f, d2 = 0.f;
#pragma unroll
  for (int c = 0; c < 8; ++c) {
    short8 q8 = *(const short8*)(d.Q + rq + c * 8);
    short8 k0 = *(const short8*)(d.K + r0 + c * 8);
    short8 k1 = *(const short8*)(d.K + r1 + c * 8);
    short8 k2 = *(const short8*)(d.K + rq + c * 8);
#pragma unroll
    for (int e = 0; e < 8; ++e) {
      const float q = bf2f((u16)q8[e]);
      d0 += q * bf2f((u16)k0[e]);
      d1 += q * bf2f((u16)k1[e]);
      d2 += q * bf2f((u16)k2[e]);
    }
  }
  const float mx = fmaxf(d0, fmaxf(d1, d2));
  float e0 = expf(d0 - mx), e1 = expf(d1 - mx), e2 = expf(d2 - mx);
  const float inv = 1.f / (e0 + e1 + e2);
  e0 *= inv; e1 *= inv; e2 *= inv;
#pragma unroll
  for (int c = 0; c < 8; ++c) {
    short8 v0 = *(const short8*)(d.V + r0 + c * 8);
    short8 v1 = *(const short8*)(d.V + r1 + c * 8);
    short8 v2 = *(const short8*)(d.V + rq + c * 8);
    short8 o8;
#pragma unroll
    for (int e = 0; e < 8; ++e)
      o8[e] = (short)f2bf(e0 * bf2f((u16)v0[e]) + e1 * bf2f((u16)v1[e]) + e2 * bf2f((u16)v2[e]));
    *(short8*)(d.O + rq + c * 8) = o8;
  }
}

// ---------------- small utility kernels ----------------
__global__ __launch_bounds__(256) void cvt_k(CvtBatch a) {
  CvtDesc d = a.d[blockIdx.y];
  const int stride = gridDim.x * 256;
  for (int i = blockIdx.x * 256 + threadIdx.x; i < d.n8; i += stride) {
    float4 x0 = ((const float4*)d.src)[i * 2];
    float4 x1 = ((const float4*)d.src)[i * 2 + 1];
    short8 r;
    r[0] = (short)f2bf(x0.x * d.scale); r[1] = (short)f2bf(x0.y * d.scale);
    r[2] = (short)f2bf(x0.z * d.scale); r[3] = (short)f2bf(x0.w * d.scale);
    r[4] = (short)f2bf(x1.x * d.scale); r[5] = (short)f2bf(x1.y * d.scale);
    r[6] = (short)f2bf(x1.z * d.scale); r[7] = (short)f2bf(x1.w * d.scale);
    *(short8*)(d.dst + (size_t)i * 8) = r;
  }
}

__global__ __launch_bounds__(256) void pos_k(float* pos) {
  const int i = blockIdx.x * 256 + threadIdx.x;  // SL*DM = 1048576
  const int dd = i & (DM - 1);
  const int s = i >> 9;
  const int j = (dd < 256) ? dd : dd - 256;
  const float inv = expf((float)j * -0.036119374f);  // -ln(10000)/255
  const float ang = (float)s * inv;
  pos[i] = (dd < 256) ? sinf(ang) : cosf(ang);
}

__global__ __launch_bounds__(256) void embed_k(EmbBatch a) {
  const int z = blockIdx.y;
  const int i = blockIdx.x * 256 + threadIdx.x;  // float4 units, 1048576
  float4 x = ((const float4*)a.src[z])[i];
  const int e = i << 2;
  const int dcol = e & (DM - 1);
  const int srow = e >> 11;
  float4 p = *(const float4*)(a.pos + (size_t)srow * DM + dcol);
  const float SC = 22.627417f;  // sqrt(512)
  float4 y{x.x * SC + p.x, x.y * SC + p.y, x.z * SC + p.z, x.w * SC + p.w};
  ((float4*)a.dst[z])[i] = y;
}

__global__ __launch_bounds__(256) void hinit_k(const float* init, float* H) {
  const int z = blockIdx.y;
  const int i = blockIdx.x * 256 + threadIdx.x;  // float4 units per slot
  float4 w = ((const float4*)(init + z * DM))[i & 127];
  ((float4*)(H + (size_t)z * RD * DM))[i] = w;
}

__global__ __launch_bounds__(256) void add_k(AddBatch a) {
  const int z = blockIdx.y;
  const int i = blockIdx.x * 256 + threadIdx.x;
  float4 x = ((const float4*)a.a[z])[i];
  float4 y = ((const float4*)a.b[z])[i];
  float4 o{x.x + y.x, x.y + y.y, x.z + y.z, x.w + y.w};
  ((float4*)a.o[z])[i] = o;
}

// ---------------- orchestration ----------------
extern "C" void kernel_launch(void* const* d_in, const int* in_sizes, int n_in,
                              void* d_out, int out_size, void* d_ws, size_t ws_size,
                              hipStream_t stream) {
  (void)in_sizes; (void)n_in; (void)out_size;
  const float* in_a  = (const float*)d_in[0];
  const float* in_t  = (const float*)d_in[1];
  const float* in_v  = (const float*)d_in[2];
  const float* initH = (const float*)d_in[3];
  const float* wq = (const float*)d_in[4];
  const float* bq = (const float*)d_in[5];
  const float* wk = (const float*)d_in[6];
  const float* bk = (const float*)d_in[7];
  const float* wv = (const float*)d_in[8];
  const float* bv = (const float*)d_in[9];
  const float* wo = (const float*)d_in[10];
  const float* bo = (const float*)d_in[11];
  const float* ln_g = (const float*)d_in[12];
  const float* ln_b = (const float*)d_in[13];
  const float* lnkv_g = (const float*)d_in[14];
  const float* lnkv_b = (const float*)d_in[15];
  const float* w1 = (const float*)d_in[16];
  const float* b1 = (const float*)d_in[17];
  const float* w2 = (const float*)d_in[18];
  const float* b2 = (const float*)d_in[19];
  const float* fln_g = (const float*)d_in[20];
  const float* fln_b = (const float*)d_in[21];
  const float* out_g = (const float*)d_in[22];
  const float* out_b = (const float*)d_in[23];
  float* out = (float*)d_out;

  char* ws = (char*)d_ws;
  // bf16 weight arena
  u16* wq_b = (u16*)(ws + 0);
  u16* wk_b = (u16*)(ws + 4718592);
  u16* wv_b = (u16*)(ws + 9437184);
  u16* wo_b = (u16*)(ws + 14155776);
  u16* w1_b = (u16*)(ws + 18874368);
  u16* w2_b = (u16*)(ws + 37748736);
  const size_t slotF = (size_t)RD * DM * 4;   // 16 MB fp32 tensor
  const size_t slotB = (size_t)RD * DM * 2;   // 8 MB bf16 tensor
  const size_t oH = 56623104;
  const size_t oS = oH + 3 * slotF;
  const size_t oX = oS + 6 * slotF;
  const int G = (ws_size >= oX + 18 * slotB) ? 3 : 1;  // group width

  float* Hs[3]; float* Ss[6];
  for (int j = 0; j < 3; ++j) Hs[j] = (float*)(ws + oH + j * slotF);
  for (int i = 0; i < 6; ++i) Ss[i] = (float*)(ws + oS + i * slotF);
  auto XN = [&](int j) { return (u16*)(ws + oX + (size_t)j * slotB); };
  auto KN = [&](int j) { return (u16*)(ws + oX + (size_t)(G + j) * slotB); };
  auto QS = [&](int j) { return (u16*)(ws + oX + (size_t)(2 * G + 3 * j) * slotB); };
  auto KS = [&](int j) { return (u16*)(ws + oX + (size_t)(2 * G + 3 * j + 1) * slotB); };
  auto VS = [&](int j) { return (u16*)(ws + oX + (size_t)(2 * G + 3 * j + 2) * slotB); };
  auto F1 = [&](int j) { return (u16*)(ws + oX + (size_t)(2 * G + 4 * j) * slotB); };

  // 1. weights fp32 -> bf16 (Q scaled by DH^-0.5)
  {
    CvtBatch cb{};
    cb.d[0] = CvtDesc{wq, wq_b, 294912, 0.125f};
    cb.d[1] = CvtDesc{wk, wk_b, 294912, 1.f};
    cb.d[2] = CvtDesc{wv, wv_b, 294912, 1.f};
    cb.d[3] = CvtDesc{wo, wo_b, 294912, 1.f};
    cb.d[4] = CvtDesc{w1, w1_b, 1179648, 1.f};
    cb.d[5] = CvtDesc{w2, w2_b, 1179648, 1.f};
    cvt_k<<<dim3(512, 6), 256, 0, stream>>>(cb);
  }
  // 2. sinusoid table (scratch; dead after embed), embed, hidden init
  float* pos = (float*)(ws + oX);
  pos_k<<<dim3(4096), 256, 0, stream>>>(pos);
  {
    EmbBatch eb{};
    eb.src[0] = in_a; eb.src[1] = in_t; eb.src[2] = in_v;
    eb.dst[0] = Ss[3]; eb.dst[1] = Ss[4]; eb.dst[2] = Ss[5];
    eb.pos = pos;
    embed_k<<<dim3(4096, 3), 256, 0, stream>>>(eb);
  }
  hinit_k<<<dim3(4096, 3), 256, 0, stream>>>(initH, (float*)(ws + oH));

  // one attention branch: LN -> QKV -> attn -> O(+res) -> fLN -> FFN1 -> FFN2(+res)
  auto run_group = [&](int g, const int* xi, float* const* ctx, const int* wi,
                       float* const* sout, float* const* fout) {
    const bool self = (ctx == nullptr);
    {
      LnBatch lb{}; int nd = 0;
      for (int j = 0; j < g; ++j)
        lb.d[nd++] = LnDesc{Hs[xi[j]], ln_g + wi[j] * DM, ln_b + wi[j] * DM, XN(j), nullptr};
      if (!self)
        for (int j = 0; j < g; ++j)
          lb.d[nd++] = LnDesc{ctx[j], lnkv_g + wi[j] * DM, lnkv_b + wi[j] * DM, KN(j), nullptr};
      ln_k<<<dim3(2048, nd), 256, 0, stream>>>(lb);
    }
    {
      GemmBatch gb{}; int nd = 0;
      for (int j = 0; j < g; ++j)
        gb.d[nd++] = GemmDesc{XN(j), wq_b + (size_t)wi[j] * DM * DM, bq + wi[j] * DM,
                              nullptr, QS(j), nullptr, 0.125f, 0};
      for (int j = 0; j < g; ++j)
        gb.d[nd++] = GemmDesc{self ? XN(j) : KN(j), wk_b + (size_t)wi[j] * DM * DM, bk + wi[j] * DM,
                              nullptr, KS(j), nullptr, 1.f, 0};
      for (int j = 0; j < g; ++j)
        gb.d[nd++] = GemmDesc{self ? XN(j) : KN(j), wv_b + (size_t)wi[j] * DM * DM, bv + wi[j] * DM,
                              nullptr, VS(j), nullptr, 1.f, 0};
      gemm_k<<<dim3(DM / BN, RD / BM, nd), 256, 0, stream>>>(gb, RD, DM, DM);
    }
    {
      AttnBatch ab{};
      for (int j = 0; j < g; ++j) ab.d[j] = AttnDesc{QS(j), KS(j), VS(j), XN(j)};
      attn_k<<<dim3(256, g), 256, 0, stream>>>(ab);
    }
    {
      GemmBatch gb{};
      for (int j = 0; j < g; ++j)
        gb.d[j] = GemmDesc{XN(j), wo_b + (size_t)wi[j] * DM * DM, bo + wi[j] * DM,
                           Hs[xi[j]], nullptr, sout[j], 1.f, 0};
      gemm_k<<<dim3(DM / BN, RD / BM, g), 256, 0, stream>>>(gb, RD, DM, DM);
    }
    {
      LnBatch lb{};
      for (int j = 0; j < g; ++j)
        lb.d[j] = LnDesc{sout[j], fln_g + wi[j] * DM, fln_b + wi[j] * DM, KN(j), nullptr};
      ln_k<<<dim3(2048, g), 256, 0, stream>>>(lb);
    }
    {
      GemmBatch gb{};
      for (int j = 0; j < g; ++j)
        gb.d[j] = GemmDesc{KN(j), w1_b + (size_t)wi[j] * DF * DM, b1 + wi[j] * DF,
                           nullptr, F1(j), nullptr, 1.f, 1};
      gemm_k<<<dim3(DF / BN, RD / BM, g), 256, 0, stream>>>(gb, RD, DF, DM);
    }
    {
      GemmBatch gb{};
      for (int j = 0; j < g; ++j)
        gb.d[j] = GemmDesc{F1(j), w2_b + (size_t)wi[j] * DF * DM, b2 + wi[j] * DM,
                           sout[j], nullptr, fout[j], 1.f, 0};
      gemm_k<<<dim3(DM / BN, RD / BM, g), 256, 0, stream>>>(gb, RD, DM, DF);
    }
  };

  // Stage A: hiddens cross-attend to embedded raw streams; FFN2 writes new H
  {
    const int xi[3] = {0, 1, 2}, wi[3] = {0, 1, 2};
    float* ctx[3] = {Ss[3], Ss[4], Ss[5]};
    float* sout[3] = {Ss[0], Ss[1], Ss[2]};
    float* fout[3] = {Hs[0], Hs[1], Hs[2]};
    for (int base = 0; base < 3; base += G) {
      const int g = (G < 3 - base) ? G : 3 - base;
      run_group(g, xi + base, ctx + base, wi + base, sout + base, fout + base);
    }
  }
  // Stage B: six cross branches (shared weight sets 3/4/5); outputs into S[0..5]
  {
    const int xi[6] = {0, 1, 2, 1, 2, 0};
    const int ci[6] = {1, 2, 0, 0, 1, 2};
    const int wi[6] = {3, 4, 5, 3, 4, 5};
    float* ctx[6]; float* sout[6];
    for (int i = 0; i < 6; ++i) { ctx[i] = Hs[ci[i]]; sout[i] = Ss[i]; }
    for (int base = 0; base < 6; base += G) {
      const int g = (G < 6 - base) ? G : 6 - base;
      run_group(g, xi + base, ctx + base, wi + base, sout + base, sout + base);
    }
  }
  // combine: h_a = h_at+h_av, h_t = h_ta+h_tv, h_v = h_va+h_vt
  {
    AddBatch ab{};
    ab.a[0] = Ss[0]; ab.b[0] = Ss[5]; ab.o[0] = Hs[0];
    ab.a[1] = Ss[3]; ab.b[1] = Ss[1]; ab.o[1] = Hs[1];
    ab.a[2] = Ss[2]; ab.b[2] = Ss[4]; ab.o[2] = Hs[2];
    add_k<<<dim3(4096, 3), 256, 0, stream>>>(ab);
  }
  // Stage C: self-attention branches (weights 6/7/8); outputs into S[0..2]
  {
    const int xi[3] = {0, 1, 2}, wi[3] = {6, 7, 8};
    float* sout[3] = {Ss[0], Ss[1], Ss[2]};
    for (int base = 0; base < 3; base += G) {
      const int g = (G < 3 - base) ? G : 3 - base;
      run_group(g, xi + base, nullptr, wi + base, sout + base, sout + base);
    }
  }
  // final LN -> d_out (3, SL, BS, D)
  {
    LnBatch lb{};
    for (int j = 0; j < 3; ++j)
      lb.d[j] = LnDesc{Ss[j], out_g, out_b, nullptr, out + (size_t)j * RD * DM};
    ln_k<<<dim3(2048, 3), 256, 0, stream>>>(lb);
  }
}

// Round 2
// 2454.226 us; speedup vs baseline: 1.1038x; 1.1038x over previous
//
#include <hip/hip_runtime.h>

#define SL 2048
#define BS 4
#define DM 512
#define NH 8
#define DH 64
#define RD 8192      // SL*BS rows
#define DF 2048      // 4*DM

#define BM 128
#define BK 32

typedef unsigned short u16;
typedef __attribute__((ext_vector_type(8))) short short8;
typedef __attribute__((ext_vector_type(4))) float f32x4;

// ---------------- helpers ----------------
__device__ __forceinline__ float bf2f(u16 u) {
  return __uint_as_float(((unsigned)u) << 16);
}
__device__ __forceinline__ u16 f2bf(float f) {
  unsigned u = __float_as_uint(f);
  unsigned r = (u + 0x7fffu + ((u >> 16) & 1u)) >> 16;  // RNE
  return (u16)r;
}

typedef __attribute__((address_space(3))) unsigned int lds_u32;
typedef __attribute__((address_space(1))) unsigned int gbl_u32;
__device__ __forceinline__ void gload_lds16(const void* g, void* l) {
  __builtin_amdgcn_global_load_lds((gbl_u32*)g, (lds_u32*)l, 16, 0, 0);
}

// ---------------- descriptors ----------------
struct GemmDesc {
  const u16* A;      // M x K row-major bf16
  const u16* B;      // N x K row-major bf16 (B^T layout)
  const float* bias; // len N (may be null)
  const float* res;  // M x N fp32 residual (may be null)
  u16* Cb;           // bf16 out (null -> fp32 out)
  float* Cf;         // fp32 out
  float bmul;        // bias multiplier
  int relu;
  int accum;         // fp32 out only: Cf[off] += (acc + bias + res)
};
struct GemmBatch { GemmDesc d[9]; };

struct LnDesc { const float* x; const float* g; const float* b; u16* yb; float* yf; };
struct LnBatch { LnDesc d[6]; };

struct AttnDesc { const u16* Q; const u16* K; const u16* V; u16* O; };
struct AttnBatch { AttnDesc d[3]; };

struct CvtDesc { const float* src; u16* dst; int n8; float scale; };
struct CvtBatch { CvtDesc d[6]; };

struct EmbBatch { const float* src[3]; float* dst[3]; const float* pos; };

// ---------------- GEMM: 128xTBN tile, BK=32, 4 waves, 2-phase dbuf, swizzled LDS ----
// LDS content at (row, chunk c) holds global (row, c ^ (row&3)); both the staging
// source address and the ds_read address apply the same XOR (rule #21).
template<int TBN>
__global__ __launch_bounds__(256) void gemm_k(GemmBatch args, int N, int K) {
  constexpr int NFR = TBN / 32;   // B fragments per wave
  constexpr int BU = TBN / 64;    // B staging units (16B x 256 threads each)
  GemmDesc g = args.d[blockIdx.z];
  __shared__ u16 As[2][BM * BK];
  __shared__ u16 Bs[2][TBN * BK];
  const int t = threadIdx.x;
  const int w = t >> 6, l = t & 63;
  const u16* Ag = g.A + (size_t)blockIdx.y * BM * K;
  const u16* Bg = g.B + (size_t)blockIdx.x * TBN * K;
  f32x4 acc[4][NFR];
#pragma unroll
  for (int m = 0; m < 4; ++m)
#pragma unroll
    for (int n = 0; n < NFR; ++n) acc[m][n] = f32x4{0.f, 0.f, 0.f, 0.f};
  const int wr = (w >> 1) * 64;
  const int wc = (w & 1) * (TBN / 2);
  const int lr = l & 15;
  const int cxo = ((l >> 4) ^ (l & 3)) << 3;  // swizzled k-chunk (elements)

  auto stage = [&](int buf, int k0) {
#pragma unroll
    for (int i = 0; i < 2; ++i) {
      const int u = (i << 8) + t;
      const int row = u >> 2;
      const int c = (u & 3) ^ (row & 3);
      gload_lds16(Ag + (size_t)row * K + k0 + (c << 3),
                  (char*)&As[buf][0] + (i << 12) + (w << 10));
    }
#pragma unroll
    for (int i = 0; i < BU; ++i) {
      const int u = (i << 8) + t;
      const int row = u >> 2;
      const int c = (u & 3) ^ (row & 3);
      gload_lds16(Bg + (size_t)row * K + k0 + (c << 3),
                  (char*)&Bs[buf][0] + (i << 12) + (w << 10));
    }
  };

  stage(0, 0);
  const int nt = K / BK;
  int cur = 0;
  for (int it = 0; it < nt; ++it) {
    __syncthreads();  // drains loads staged one iteration ago (they had a full compute phase)
    if (it + 1 < nt) stage(cur ^ 1, (it + 1) * BK);
    const u16* Ab = &As[cur][0];
    const u16* Bb = &Bs[cur][0];
    short8 af[4], bfr[NFR];
#pragma unroll
    for (int m = 0; m < 4; ++m)
      af[m] = *(const short8*)(Ab + (wr + m * 16 + lr) * BK + cxo);
#pragma unroll
    for (int n = 0; n < NFR; ++n)
      bfr[n] = *(const short8*)(Bb + (wc + n * 16 + lr) * BK + cxo);
#pragma unroll
    for (int m = 0; m < 4; ++m)
#pragma unroll
      for (int n = 0; n < NFR; ++n)
        acc[m][n] = __builtin_amdgcn_mfma_f32_16x16x32_bf16(af[m], bfr[n], acc[m][n], 0, 0, 0);
    cur ^= 1;
  }

  const int c0 = blockIdx.x * TBN + wc + lr;
  const int r0 = blockIdx.y * BM + wr + ((l >> 4) << 2);
#pragma unroll
  for (int n = 0; n < NFR; ++n) {
    const int gc = c0 + n * 16;
    const float bi = g.bias ? g.bias[gc] * g.bmul : 0.f;
#pragma unroll
    for (int m = 0; m < 4; ++m) {
#pragma unroll
      for (int r = 0; r < 4; ++r) {
        const size_t off = (size_t)(r0 + m * 16 + r) * N + gc;
        float v = acc[m][n][r] + bi;
        if (g.res) v += g.res[off];
        if (g.relu) v = fmaxf(v, 0.f);
        if (g.Cb) {
          g.Cb[off] = f2bf(v);
        } else {
          if (g.accum) v += g.Cf[off];
          g.Cf[off] = v;
        }
      }
    }
  }
}

// ---------------- LayerNorm: wave-per-row, D=512, 8 floats/lane ----------------
__global__ __launch_bounds__(256) void ln_k(LnBatch args) {
  LnDesc d = args.d[blockIdx.y];
  const int row = blockIdx.x * 4 + (threadIdx.x >> 6);
  const int l = threadIdx.x & 63;
  const float* xp = d.x + (size_t)row * DM + l * 8;
  float4 x0 = *(const float4*)xp;
  float4 x1 = *(const float4*)(xp + 4);
  float xv[8] = {x0.x, x0.y, x0.z, x0.w, x1.x, x1.y, x1.z, x1.w};
  float s = 0.f, ss = 0.f;
#pragma unroll
  for (int j = 0; j < 8; ++j) { s += xv[j]; ss += xv[j] * xv[j]; }
#pragma unroll
  for (int m = 1; m < 64; m <<= 1) {
    s += __shfl_xor(s, m, 64);
    ss += __shfl_xor(ss, m, 64);
  }
  const float mean = s * (1.f / DM);
  const float var = ss * (1.f / DM) - mean * mean;
  const float rstd = rsqrtf(var + 1e-5f);
  float4 g0 = *(const float4*)(d.g + l * 8);
  float4 g1 = *(const float4*)(d.g + l * 8 + 4);
  float4 b0 = *(const float4*)(d.b + l * 8);
  float4 b1 = *(const float4*)(d.b + l * 8 + 4);
  float gv[8] = {g0.x, g0.y, g0.z, g0.w, g1.x, g1.y, g1.z, g1.w};
  float bv[8] = {b0.x, b0.y, b0.z, b0.w, b1.x, b1.y, b1.z, b1.w};
  float y[8];
#pragma unroll
  for (int j = 0; j < 8; ++j) y[j] = (xv[j] - mean) * rstd * gv[j] + bv[j];
  if (d.yb) {
    short8 p;
#pragma unroll
    for (int j = 0; j < 8; ++j) p[j] = (short)f2bf(y[j]);
    *(short8*)(d.yb + (size_t)row * DM + l * 8) = p;
  } else {
    float* o = d.yf + (size_t)row * DM + l * 8;
    *(float4*)o = float4{y[0], y[1], y[2], y[3]};
    *(float4*)(o + 4) = float4{y[4], y[5], y[6], y[7]};
  }
}

// ---------------- windowed attention (PF=3, positions s-2,s-1,s mod SL) ----------------
__global__ __launch_bounds__(256) void attn_k(AttnBatch args) {
  AttnDesc d = args.d[blockIdx.y];
  const int idx = blockIdx.x * 256 + threadIdx.x;  // (s,b,h), 65536 total
  const int h = idx & 7;
  const int b = (idx >> 3) & 3;
  const int s = idx >> 5;
  const int s0 = (s + SL - 2) & (SL - 1);
  const int s1 = (s + SL - 1) & (SL - 1);
  const size_t rq = (size_t)(s * BS + b) * DM + h * DH;
  const size_t r0 = (size_t)(s0 * BS + b) * DM + h * DH;
  const size_t r1 = (size_t)(s1 * BS + b) * DM + h * DH;
  float d0 = 0.f, d1 = 0.f, d2 = 0.f;
#pragma unroll
  for (int c = 0; c < 8; ++c) {
    short8 q8 = *(const short8*)(d.Q + rq + c * 8);
    short8 k0 = *(const short8*)(d.K + r0 + c * 8);
    short8 k1 = *(const short8*)(d.K + r1 + c * 8);
    short8 k2 = *(const short8*)(d.K + rq + c * 8);
#pragma unroll
    for (int e = 0; e < 8; ++e) {
      const float q = bf2f((u16)q8[e]);
      d0 += q * bf2f((u16)k0[e]);
      d1 += q * bf2f((u16)k1[e]);
      d2 += q * bf2f((u16)k2[e]);
    }
  }
  const float mx = fmaxf(d0, fmaxf(d1, d2));
  float e0 = expf(d0 - mx), e1 = expf(d1 - mx), e2 = expf(d2 - mx);
  const float inv = 1.f / (e0 + e1 + e2);
  e0 *= inv; e1 *= inv; e2 *= inv;
#pragma unroll
  for (int c = 0; c < 8; ++c) {
    short8 v0 = *(const short8*)(d.V + r0 + c * 8);
    short8 v1 = *(const short8*)(d.V + r1 + c * 8);
    short8 v2 = *(const short8*)(d.V + rq + c * 8);
    short8 o8;
#pragma unroll
    for (int e = 0; e < 8; ++e)
      o8[e] = (short)f2bf(e0 * bf2f((u16)v0[e]) + e1 * bf2f((u16)v1[e]) + e2 * bf2f((u16)v2[e]));
    *(short8*)(d.O + rq + c * 8) = o8;
  }
}

// ---------------- small utility kernels ----------------
__global__ __launch_bounds__(256) void cvt_k(CvtBatch a) {
  CvtDesc d = a.d[blockIdx.y];
  const int stride = gridDim.x * 256;
  for (int i = blockIdx.x * 256 + threadIdx.x; i < d.n8; i += stride) {
    float4 x0 = ((const float4*)d.src)[i * 2];
    float4 x1 = ((const float4*)d.src)[i * 2 + 1];
    short8 r;
    r[0] = (short)f2bf(x0.x * d.scale); r[1] = (short)f2bf(x0.y * d.scale);
    r[2] = (short)f2bf(x0.z * d.scale); r[3] = (short)f2bf(x0.w * d.scale);
    r[4] = (short)f2bf(x1.x * d.scale); r[5] = (short)f2bf(x1.y * d.scale);
    r[6] = (short)f2bf(x1.z * d.scale); r[7] = (short)f2bf(x1.w * d.scale);
    *(short8*)(d.dst + (size_t)i * 8) = r;
  }
}

__global__ __launch_bounds__(256) void pos_k(float* pos) {
  const int i = blockIdx.x * 256 + threadIdx.x;  // SL*DM = 1048576
  const int dd = i & (DM - 1);
  const int s = i >> 9;
  const int j = (dd < 256) ? dd : dd - 256;
  const float inv = expf((float)j * -0.036119374f);  // -ln(10000)/255
  const float ang = (float)s * inv;
  pos[i] = (dd < 256) ? sinf(ang) : cosf(ang);
}

__global__ __launch_bounds__(256) void embed_k(EmbBatch a) {
  const int z = blockIdx.y;
  const int i = blockIdx.x * 256 + threadIdx.x;  // float4 units, 1048576
  float4 x = ((const float4*)a.src[z])[i];
  const int e = i << 2;
  const int dcol = e & (DM - 1);
  const int srow = e >> 11;
  float4 p = *(const float4*)(a.pos + (size_t)srow * DM + dcol);
  const float SC = 22.627417f;  // sqrt(512)
  float4 y{x.x * SC + p.x, x.y * SC + p.y, x.z * SC + p.z, x.w * SC + p.w};
  ((float4*)a.dst[z])[i] = y;
}

__global__ __launch_bounds__(256) void hinit_k(const float* init, float* H) {
  const int z = blockIdx.y;
  const int i = blockIdx.x * 256 + threadIdx.x;  // float4 units per slot
  float4 w = ((const float4*)(init + z * DM))[i & 127];
  ((float4*)(H + (size_t)z * RD * DM))[i] = w;
}

// ---------------- orchestration ----------------
extern "C" void kernel_launch(void* const* d_in, const int* in_sizes, int n_in,
                              void* d_out, int out_size, void* d_ws, size_t ws_size,
                              hipStream_t stream) {
  (void)in_sizes; (void)n_in; (void)out_size;
  const float* in_a  = (const float*)d_in[0];
  const float* in_t  = (const float*)d_in[1];
  const float* in_v  = (const float*)d_in[2];
  const float* initH = (const float*)d_in[3];
  const float* wq = (const float*)d_in[4];
  const float* bq = (const float*)d_in[5];
  const float* wk = (const float*)d_in[6];
  const float* bk = (const float*)d_in[7];
  const float* wv = (const float*)d_in[8];
  const float* bv = (const float*)d_in[9];
  const float* wo = (const float*)d_in[10];
  const float* bo = (const float*)d_in[11];
  const float* ln_g = (const float*)d_in[12];
  const float* ln_b = (const float*)d_in[13];
  const float* lnkv_g = (const float*)d_in[14];
  const float* lnkv_b = (const float*)d_in[15];
  const float* w1 = (const float*)d_in[16];
  const float* b1 = (const float*)d_in[17];
  const float* w2 = (const float*)d_in[18];
  const float* b2 = (const float*)d_in[19];
  const float* fln_g = (const float*)d_in[20];
  const float* fln_b = (const float*)d_in[21];
  const float* out_g = (const float*)d_in[22];
  const float* out_b = (const float*)d_in[23];
  float* out = (float*)d_out;

  char* ws = (char*)d_ws;
  // bf16 weight arena (56.6 MB)
  u16* wq_b = (u16*)(ws + 0);
  u16* wk_b = (u16*)(ws + 4718592);
  u16* wv_b = (u16*)(ws + 9437184);
  u16* wo_b = (u16*)(ws + 14155776);
  u16* w1_b = (u16*)(ws + 18874368);
  u16* w2_b = (u16*)(ws + 37748736);
  const size_t slotF = (size_t)RD * DM * 4;   // 16 MB fp32 tensor
  const size_t slotB = (size_t)RD * DM * 2;   // 8 MB bf16 tensor
  const size_t oH = 56623104;
  const size_t oS = oH + 3 * slotF;
  const size_t oX = oS + 6 * slotF;
  // group width: X region needs 5*G bf16 slots
  int G = 1;
  if (ws_size >= oX + 15 * slotB) G = 3;
  else if (ws_size >= oX + 10 * slotB) G = 2;

  float* Hs[3]; float* Ss[6];
  for (int j = 0; j < 3; ++j) Hs[j] = (float*)(ws + oH + j * slotF);
  for (int i = 0; i < 6; ++i) Ss[i] = (float*)(ws + oS + i * slotF);
  auto SLOT = [&](int j) { return (u16*)(ws + oX + (size_t)j * slotB); };
  auto KN = [&](int j) { return SLOT(j); };            // live until FFN1 reads it
  auto XN = [&](int j) { return SLOT(G + j); };        // dead after O-proj
  auto QS = [&](int j) { return SLOT(2 * G + 3 * j); };
  auto KS = [&](int j) { return SLOT(2 * G + 3 * j + 1); };
  auto VS = [&](int j) { return SLOT(2 * G + 3 * j + 2); };
  auto F1 = [&](int j) { return SLOT(G + 4 * j); };    // aliases XN + QS/KS/VS (both dead)

  // 1. weights fp32 -> bf16 (Q weight pre-scaled by DH^-0.5)
  {
    CvtBatch cb{};
    cb.d[0] = CvtDesc{wq, wq_b, 294912, 0.125f};
    cb.d[1] = CvtDesc{wk, wk_b, 294912, 1.f};
    cb.d[2] = CvtDesc{wv, wv_b, 294912, 1.f};
    cb.d[3] = CvtDesc{wo, wo_b, 294912, 1.f};
    cb.d[4] = CvtDesc{w1, w1_b, 1179648, 1.f};
    cb.d[5] = CvtDesc{w2, w2_b, 1179648, 1.f};
    cvt_k<<<dim3(512, 6), 256, 0, stream>>>(cb);
  }
  // 2. sinusoid table (in X scratch; dead after embed), embed, hidden init
  float* pos = (float*)(ws + oX);
  pos_k<<<dim3(4096), 256, 0, stream>>>(pos);
  {
    EmbBatch eb{};
    eb.src[0] = in_a; eb.src[1] = in_t; eb.src[2] = in_v;
    eb.dst[0] = Ss[3]; eb.dst[1] = Ss[4]; eb.dst[2] = Ss[5];
    eb.pos = pos;
    embed_k<<<dim3(4096, 3), 256, 0, stream>>>(eb);
  }
  hinit_k<<<dim3(4096, 3), 256, 0, stream>>>(initH, (float*)(ws + oH));

  // one branch chunk: LN -> QKV -> attn -> O(+res) -> fLN -> FFN1 -> FFN2(+res[,accum])
  auto run_group = [&](int g, float* const* xv, float* const* ctx, const int* wi,
                       float* const* sout, float* const* fout, int accum) {
    {
      LnBatch lb{}; int nd = 0;
      for (int j = 0; j < g; ++j)
        lb.d[nd++] = LnDesc{xv[j], ln_g + wi[j] * DM, ln_b + wi[j] * DM, XN(j), nullptr};
      if (ctx)
        for (int j = 0; j < g; ++j)
          lb.d[nd++] = LnDesc{ctx[j], lnkv_g + wi[j] * DM, lnkv_b + wi[j] * DM, KN(j), nullptr};
      ln_k<<<dim3(2048, nd), 256, 0, stream>>>(lb);
    }
    {
      GemmBatch gb{}; int nd = 0;
      for (int j = 0; j < g; ++j)
        gb.d[nd++] = GemmDesc{XN(j), wq_b + (size_t)wi[j] * DM * DM, bq + wi[j] * DM,
                              nullptr, QS(j), nullptr, 0.125f, 0, 0};
      for (int j = 0; j < g; ++j)
        gb.d[nd++] = GemmDesc{ctx ? KN(j) : XN(j), wk_b + (size_t)wi[j] * DM * DM, bk + wi[j] * DM,
                              nullptr, KS(j), nullptr, 1.f, 0, 0};
      for (int j = 0; j < g; ++j)
        gb.d[nd++] = GemmDesc{ctx ? KN(j) : XN(j), wv_b + (size_t)wi[j] * DM * DM, bv + wi[j] * DM,
                              nullptr, VS(j), nullptr, 1.f, 0, 0};
      gemm_k<64><<<dim3(DM / 64, RD / BM, nd), 256, 0, stream>>>(gb, DM, DM);
    }
    {
      AttnBatch ab{};
      for (int j = 0; j < g; ++j) ab.d[j] = AttnDesc{QS(j), KS(j), VS(j), XN(j)};
      attn_k<<<dim3(256, g), 256, 0, stream>>>(ab);
    }
    {
      GemmBatch gb{};
      for (int j = 0; j < g; ++j)
        gb.d[j] = GemmDesc{XN(j), wo_b + (size_t)wi[j] * DM * DM, bo + wi[j] * DM,
                           xv[j], nullptr, sout[j], 1.f, 0, 0};
      gemm_k<64><<<dim3(DM / 64, RD / BM, g), 256, 0, stream>>>(gb, DM, DM);
    }
    {
      LnBatch lb{};
      for (int j = 0; j < g; ++j)
        lb.d[j] = LnDesc{sout[j], fln_g + wi[j] * DM, fln_b + wi[j] * DM, KN(j), nullptr};
      ln_k<<<dim3(2048, g), 256, 0, stream>>>(lb);
    }
    {
      GemmBatch gb{};
      for (int j = 0; j < g; ++j)
        gb.d[j] = GemmDesc{KN(j), w1_b + (size_t)wi[j] * DF * DM, b1 + wi[j] * DF,
                           nullptr, F1(j), nullptr, 1.f, 1, 0};
      gemm_k<128><<<dim3(DF / 128, RD / BM, g), 256, 0, stream>>>(gb, DF, DM);
    }
    {
      GemmBatch gb{};
      for (int j = 0; j < g; ++j)
        gb.d[j] = GemmDesc{F1(j), w2_b + (size_t)wi[j] * DM * DF, b2 + wi[j] * DM,
                           sout[j], nullptr, fout[j], 1.f, 0, accum};
      gemm_k<64><<<dim3(DM / 64, RD / BM, g), 256, 0, stream>>>(gb, DM, DF);
    }
  };

  auto drive = [&](int n, float* const* xv, float* const* ctx, const int* wi,
                   float* const* sout, float* const* fout, int accum) {
    for (int b = 0; b < n; b += G) {
      const int g = (G < n - b) ? G : n - b;
      run_group(g, xv + b, ctx ? ctx + b : nullptr, wi + b, sout + b, fout + b, accum);
    }
  };

  // Stage A: hiddens (broadcast init) cross-attend to embedded raw streams
  {
    float* xv[3] = {Hs[0], Hs[1], Hs[2]};
    float* ctx[3] = {Ss[3], Ss[4], Ss[5]};
    const int wi[3] = {0, 1, 2};
    float* sout[3] = {Ss[0], Ss[1], Ss[2]};
    float* fout[3] = {Hs[0], Hs[1], Hs[2]};
    drive(3, xv, ctx, wi, sout, fout, 0);
  }
  // Stage B group 1: (at, tv, va) -> Ss[0..2] (FFN2 in-place over sout)
  {
    float* xv[3] = {Hs[0], Hs[1], Hs[2]};
    float* ctx[3] = {Hs[1], Hs[2], Hs[0]};
    const int wi[3] = {3, 4, 5};
    float* sout[3] = {Ss[0], Ss[1], Ss[2]};
    drive(3, xv, ctx, wi, sout, sout, 0);
  }
  // Stage B group 2: (ta, vt, av) accumulate into the pairwise sums:
  // new h_t = h_tv + h_ta -> Ss[1]; new h_v = h_va + h_vt -> Ss[2]; new h_a = h_at + h_av -> Ss[0]
  {
    float* xv[3] = {Hs[1], Hs[2], Hs[0]};
    float* ctx[3] = {Hs[0], Hs[1], Hs[2]};
    const int wi[3] = {3, 4, 5};
    float* sout[3] = {Ss[3], Ss[4], Ss[5]};
    float* fout[3] = {Ss[1], Ss[2], Ss[0]};
    drive(3, xv, ctx, wi, sout, fout, 1);
  }
  // Stage C: self-attention on the new hiddens -> Hs[0..2]
  {
    float* xv[3] = {Ss[0], Ss[1], Ss[2]};
    const int wi[3] = {6, 7, 8};
    float* sout[3] = {Ss[3], Ss[4], Ss[5]};
    float* fout[3] = {Hs[0], Hs[1], Hs[2]};
    drive(3, xv, nullptr, wi, sout, fout, 0);
  }
  // final LN -> d_out (3, SL, BS, D)
  {
    LnBatch lb{};
    for (int j = 0; j < 3; ++j)
      lb.d[j] = LnDesc{Hs[j], out_g, out_b, nullptr, out + (size_t)j * RD * DM};
    ln_k<<<dim3(2048, 3), 256, 0, stream>>>(lb);
  }
}

// Round 4
// 2246.360 us; speedup vs baseline: 1.2059x; 1.0925x over previous
//
#include <hip/hip_runtime.h>

#define SL 2048
#define BS 4
#define DM 512
#define NH 8
#define DH 64
#define RD 8192      // SL*BS rows
#define DF 2048      // 4*DM
#define BK 32

typedef unsigned short u16;
typedef __attribute__((ext_vector_type(8))) short short8;
typedef __attribute__((ext_vector_type(4))) float f32x4;

__device__ __forceinline__ float bf2f(u16 u) {
  return __uint_as_float(((unsigned)u) << 16);
}
__device__ __forceinline__ u16 f2bf(float f) {
  unsigned u = __float_as_uint(f);
  unsigned r = (u + 0x7fffu + ((u >> 16) & 1u)) >> 16;  // RNE
  return (u16)r;
}

typedef __attribute__((address_space(3))) unsigned int lds_u32;
typedef __attribute__((address_space(1))) unsigned int gbl_u32;
__device__ __forceinline__ void gload_lds16(const void* g, void* l) {
  __builtin_amdgcn_global_load_lds((gbl_u32*)g, (lds_u32*)l, 16, 0, 0);
}

// ---------------- descriptors ----------------
struct GemmDesc {
  const u16* A;      // 8192 x K row-major bf16 (row stride = K)
  const u16* B;      // nrows x K bf16 (B^T layout, row stride = ldb)
  const float* bias; // indexed by local col (may be null)
  const float* res;  // fp32 residual at ldc stride (may be null)
  u16* Cb;           // bf16 out (null -> fp32 out)
  float* Cf;         // fp32 out
  int K;
  int ldb;           // B row stride (elements)
  int nx;            // active x-blocks
  int ldc;           // output row stride (elements)
  int col0;          // output column offset
  int relu;
  int accum;         // fp32 only: also add existing Cf
};
struct GemmBatch { GemmDesc d[9]; };

struct LnDesc {
  const float* x;    // fp32 input (or null when raw-mode)
  const float* raw;  // raw input for fused embed (x = raw*sqrt(D)+pos)
  const float* pos;
  const float* g; const float* b;
  u16* yb; float* yf;
};
struct LnBatch { LnDesc d[6]; };

struct AttnDesc { const u16* PK; u16* O; };  // PK: packed [8192][1536] Q|K|V
struct AttnBatch { AttnDesc d[3]; };

struct CvtDesc { const float* src; u16* dst; int n8; };
struct CvtBatch { CvtDesc d[3]; };

// ---- GEMM: 128 x TBN tile, BK=32, 4 waves, 2-phase dbuf, conflict-free LDS swizzle,
// ---- XCD-contiguous-M block swizzle. gridDim.y must be 64.
template<int TBN>
__global__ __launch_bounds__(256) void gemm_k(GemmBatch args) {
  constexpr int NFR = TBN / 32;   // B fragments per wave
  constexpr int BU = TBN / 64;    // B staging rounds
  const GemmDesc g = args.d[blockIdx.z];
  __shared__ u16 As[2][128 * BK];
  __shared__ u16 Bs[2][TBN * BK];
  const int gX = gridDim.x;
  const int nwg = gX << 6;
  const int orig = blockIdx.y * gX + blockIdx.x;
  const int swz = (orig & 7) * (nwg >> 3) + (orig >> 3);  // XCD gets contiguous M rows
  const int by = swz / gX;
  const int bx = swz - by * gX;
  if (bx >= g.nx) return;
  const int K = g.K;
  const int ldb = g.ldb;
  const int t = threadIdx.x;
  const int w = t >> 6, l = t & 63;
  const u16* Ag = g.A + (size_t)by * 128 * K;
  const u16* Bg = g.B + (size_t)bx * TBN * ldb;
  f32x4 acc[4][NFR];
#pragma unroll
  for (int m = 0; m < 4; ++m)
#pragma unroll
    for (int n = 0; n < NFR; ++n) acc[m][n] = f32x4{0.f, 0.f, 0.f, 0.f};
  const int wr = (w >> 1) * 64;
  const int wc = (w & 1) * (TBN / 2);
  const int lr = l & 15;
  // LDS(row, chunk q) holds global(row, q ^ ((row>>1)&3)); 16B-slot (4*row+q)%8
  // is then bijective per 8 rows -> 2-way max (free per m136).
  const int cxo = ((l >> 4) ^ ((l >> 1) & 3)) << 3;  // swizzled k-chunk (elements)

  auto stage = [&](int buf, int k0) {
#pragma unroll
    for (int i = 0; i < 2; ++i) {
      const int u = (i << 8) + t;
      const int row = u >> 2;
      const int c = (u & 3) ^ ((row >> 1) & 3);
      gload_lds16(Ag + (size_t)row * K + k0 + (c << 3),
                  (char*)&As[buf][0] + (i << 12) + (w << 10));
    }
#pragma unroll
    for (int i = 0; i < BU; ++i) {
      const int u = (i << 8) + t;
      const int row = u >> 2;
      const int c = (u & 3) ^ ((row >> 1) & 3);
      gload_lds16(Bg + (size_t)row * ldb + k0 + (c << 3),
                  (char*)&Bs[buf][0] + (i << 12) + (w << 10));
    }
  };

  stage(0, 0);
  const int nt = K / BK;
  int cur = 0;
  for (int it = 0; it < nt; ++it) {
    __syncthreads();  // drains loads staged last iter (they had a full compute phase)
    if (it + 1 < nt) stage(cur ^ 1, (it + 1) * BK);
    const u16* Ab = &As[cur][0];
    const u16* Bb = &Bs[cur][0];
    short8 af[4], bfr[NFR];
#pragma unroll
    for (int m = 0; m < 4; ++m)
      af[m] = *(const short8*)(Ab + (wr + m * 16 + lr) * BK + cxo);
#pragma unroll
    for (int n = 0; n < NFR; ++n)
      bfr[n] = *(const short8*)(Bb + (wc + n * 16 + lr) * BK + cxo);
#pragma unroll
    for (int m = 0; m < 4; ++m)
#pragma unroll
      for (int n = 0; n < NFR; ++n)
        acc[m][n] = __builtin_amdgcn_mfma_f32_16x16x32_bf16(af[m], bfr[n], acc[m][n], 0, 0, 0);
    cur ^= 1;
  }

  const int c0 = bx * TBN + wc + lr;    // local output col
  const int r0 = by * 128 + wr + ((l >> 4) << 2);
#pragma unroll
  for (int n = 0; n < NFR; ++n) {
    const int gc = c0 + n * 16;
    const float bi = g.bias ? g.bias[gc] : 0.f;
#pragma unroll
    for (int m = 0; m < 4; ++m) {
#pragma unroll
      for (int r = 0; r < 4; ++r) {
        const size_t off = (size_t)(r0 + m * 16 + r) * g.ldc + g.col0 + gc;
        float v = acc[m][n][r] + bi;
        if (g.res) v += g.res[off];
        if (g.relu) v = fmaxf(v, 0.f);
        if (g.Cb) {
          g.Cb[off] = f2bf(v);
        } else {
          if (g.accum) v += g.Cf[off];
          g.Cf[off] = v;
        }
      }
    }
  }
}

// ---------------- LayerNorm (optionally fused embed: x = raw*sqrt(D)+pos) ----------
__global__ __launch_bounds__(256) void ln_k(LnBatch args) {
  LnDesc d = args.d[blockIdx.y];
  const int row = blockIdx.x * 4 + (threadIdx.x >> 6);
  const int l = threadIdx.x & 63;
  float xv[8];
  if (d.raw) {
    const float* rp = d.raw + (size_t)row * DM + l * 8;
    const float* pp = d.pos + (size_t)(row >> 2) * DM + l * 8;
    float4 r0 = *(const float4*)rp, r1 = *(const float4*)(rp + 4);
    float4 p0 = *(const float4*)pp, p1 = *(const float4*)(pp + 4);
    const float SC = 22.627416998f;  // sqrt(512)
    xv[0] = r0.x * SC + p0.x; xv[1] = r0.y * SC + p0.y;
    xv[2] = r0.z * SC + p0.z; xv[3] = r0.w * SC + p0.w;
    xv[4] = r1.x * SC + p1.x; xv[5] = r1.y * SC + p1.y;
    xv[6] = r1.z * SC + p1.z; xv[7] = r1.w * SC + p1.w;
  } else {
    const float* xp = d.x + (size_t)row * DM + l * 8;
    float4 x0 = *(const float4*)xp, x1 = *(const float4*)(xp + 4);
    xv[0] = x0.x; xv[1] = x0.y; xv[2] = x0.z; xv[3] = x0.w;
    xv[4] = x1.x; xv[5] = x1.y; xv[6] = x1.z; xv[7] = x1.w;
  }
  float s = 0.f, ss = 0.f;
#pragma unroll
  for (int j = 0; j < 8; ++j) { s += xv[j]; ss += xv[j] * xv[j]; }
#pragma unroll
  for (int m = 1; m < 64; m <<= 1) {
    s += __shfl_xor(s, m, 64);
    ss += __shfl_xor(ss, m, 64);
  }
  const float mean = s * (1.f / DM);
  const float var = ss * (1.f / DM) - mean * mean;
  const float rstd = rsqrtf(var + 1e-5f);
  float4 g0 = *(const float4*)(d.g + l * 8);
  float4 g1 = *(const float4*)(d.g + l * 8 + 4);
  float4 b0 = *(const float4*)(d.b + l * 8);
  float4 b1 = *(const float4*)(d.b + l * 8 + 4);
  float gv[8] = {g0.x, g0.y, g0.z, g0.w, g1.x, g1.y, g1.z, g1.w};
  float bv[8] = {b0.x, b0.y, b0.z, b0.w, b1.x, b1.y, b1.z, b1.w};
  float y[8];
#pragma unroll
  for (int j = 0; j < 8; ++j) y[j] = (xv[j] - mean) * rstd * gv[j] + bv[j];
  if (d.yb) {
    short8 p;
#pragma unroll
    for (int j = 0; j < 8; ++j) p[j] = (short)f2bf(y[j]);
    *(short8*)(d.yb + (size_t)row * DM + l * 8) = p;
  } else {
    float* o = d.yf + (size_t)row * DM + l * 8;
    *(float4*)o = float4{y[0], y[1], y[2], y[3]};
    *(float4*)(o + 4) = float4{y[4], y[5], y[6], y[7]};
  }
}

// ---- windowed attention over packed QKV [8192][1536] (PF=3: s-2, s-1, s mod SL) ----
__global__ __launch_bounds__(256) void attn_k(AttnBatch args) {
  AttnDesc d = args.d[blockIdx.y];
  const int idx = blockIdx.x * 256 + threadIdx.x;  // (s,b,h), 65536 total
  const int h = idx & 7;
  const int b = (idx >> 3) & 3;
  const int s = idx >> 5;
  const int s0 = (s + SL - 2) & (SL - 1);
  const int s1 = (s + SL - 1) & (SL - 1);
  const size_t bq_ = (size_t)(s * BS + b) * 1536 + h * DH;
  const size_t b0 = (size_t)(s0 * BS + b) * 1536 + h * DH;
  const size_t b1 = (size_t)(s1 * BS + b) * 1536 + h * DH;
  float d0 = 0.f, d1 = 0.f, d2 = 0.f;
#pragma unroll
  for (int c = 0; c < 8; ++c) {
    short8 q8 = *(const short8*)(d.PK + bq_ + c * 8);
    short8 k0 = *(const short8*)(d.PK + b0 + 512 + c * 8);
    short8 k1 = *(const short8*)(d.PK + b1 + 512 + c * 8);
    short8 k2 = *(const short8*)(d.PK + bq_ + 512 + c * 8);
#pragma unroll
    for (int e = 0; e < 8; ++e) {
      const float q = bf2f((u16)q8[e]);
      d0 += q * bf2f((u16)k0[e]);
      d1 += q * bf2f((u16)k1[e]);
      d2 += q * bf2f((u16)k2[e]);
    }
  }
  const float mx = fmaxf(d0, fmaxf(d1, d2));
  float e0 = expf(d0 - mx), e1 = expf(d1 - mx), e2 = expf(d2 - mx);
  const float inv = 1.f / (e0 + e1 + e2);
  e0 *= inv; e1 *= inv; e2 *= inv;
  const size_t ro = (size_t)(s * BS + b) * DM + h * DH;
#pragma unroll
  for (int c = 0; c < 8; ++c) {
    short8 v0 = *(const short8*)(d.PK + b0 + 1024 + c * 8);
    short8 v1 = *(const short8*)(d.PK + b1 + 1024 + c * 8);
    short8 v2 = *(const short8*)(d.PK + bq_ + 1024 + c * 8);
    short8 o8;
#pragma unroll
    for (int e = 0; e < 8; ++e)
      o8[e] = (short)f2bf(e0 * bf2f((u16)v0[e]) + e1 * bf2f((u16)v1[e]) + e2 * bf2f((u16)v2[e]));
    *(short8*)(d.O + ro + c * 8) = o8;
  }
}

// ---------------- setup kernels ----------------
__global__ __launch_bounds__(256) void packqkv_k(const float* wq, const float* wk,
                                                 const float* wv, u16* dst) {
  const int i = blockIdx.x * 256 + threadIdx.x;  // 884736 short8 units
  const int br = i / 98304;                      // 1536*512/8
  const int r = i - br * 98304;
  const int sec = r / 32768;                     // 512*512/8
  const int r2 = r - sec * 32768;
  const float* src = (sec == 0) ? wq : (sec == 1) ? wk : wv;
  const float* sp = src + (size_t)br * 262144 + (size_t)r2 * 8;
  const float sc = (sec == 0) ? 0.125f : 1.f;    // fold DH^-0.5 into Q
  short8 o;
#pragma unroll
  for (int e = 0; e < 8; ++e) o[e] = (short)f2bf(sp[e] * sc);
  *(short8*)(dst + (size_t)br * 786432 + (size_t)sec * 262144 + (size_t)r2 * 8) = o;
}

__global__ __launch_bounds__(256) void packbias_k(const float* bq, const float* bk,
                                                  const float* bv, float* dst) {
  const int i = blockIdx.x * 256 + threadIdx.x;  // 13824
  if (i >= 13824) return;
  const int br = i / 1536;
  const int r = i - br * 1536;
  const int sec = r >> 9;
  const int j = r & 511;
  float v = (sec == 0) ? bq[br * 512 + j] * 0.125f
          : (sec == 1) ? bk[br * 512 + j] : bv[br * 512 + j];
  dst[i] = v;
}

__global__ __launch_bounds__(256) void cvt_k(CvtBatch a) {
  CvtDesc d = a.d[blockIdx.y];
  const int stride = gridDim.x * 256;
  for (int i = blockIdx.x * 256 + threadIdx.x; i < d.n8; i += stride) {
    float4 x0 = ((const float4*)d.src)[i * 2];
    float4 x1 = ((const float4*)d.src)[i * 2 + 1];
    short8 r;
    r[0] = (short)f2bf(x0.x); r[1] = (short)f2bf(x0.y);
    r[2] = (short)f2bf(x0.z); r[3] = (short)f2bf(x0.w);
    r[4] = (short)f2bf(x1.x); r[5] = (short)f2bf(x1.y);
    r[6] = (short)f2bf(x1.z); r[7] = (short)f2bf(x1.w);
    *(short8*)(d.dst + (size_t)i * 8) = r;
  }
}

__global__ __launch_bounds__(256) void pos_k(float* pos) {
  const int i = blockIdx.x * 256 + threadIdx.x;  // SL*DM
  const int dd = i & (DM - 1);
  const int s = i >> 9;
  const int j = (dd < 256) ? dd : dd - 256;
  const float inv = expf((float)j * -0.036119374f);  // -ln(10000)/255
  const float ang = (float)s * inv;
  pos[i] = (dd < 256) ? sinf(ang) : cosf(ang);
}

__global__ __launch_bounds__(256) void hinit_k(const float* init, float* H) {
  const int z = blockIdx.y;
  const int i = blockIdx.x * 256 + threadIdx.x;
  float4 w = ((const float4*)(init + z * DM))[i & 127];
  ((float4*)(H + (size_t)z * RD * DM))[i] = w;
}

// ---------------- orchestration ----------------
extern "C" void kernel_launch(void* const* d_in, const int* in_sizes, int n_in,
                              void* d_out, int out_size, void* d_ws, size_t ws_size,
                              hipStream_t stream) {
  (void)in_sizes; (void)n_in; (void)out_size;
  const float* in_a  = (const float*)d_in[0];
  const float* in_t  = (const float*)d_in[1];
  const float* in_v  = (const float*)d_in[2];
  const float* initH = (const float*)d_in[3];
  const float* wq = (const float*)d_in[4];
  const float* bq = (const float*)d_in[5];
  const float* wk = (const float*)d_in[6];
  const float* bk = (const float*)d_in[7];
  const float* wv = (const float*)d_in[8];
  const float* bv = (const float*)d_in[9];
  const float* wo = (const float*)d_in[10];
  const float* bo = (const float*)d_in[11];
  const float* ln_g = (const float*)d_in[12];
  const float* ln_b = (const float*)d_in[13];
  const float* lnkv_g = (const float*)d_in[14];
  const float* lnkv_b = (const float*)d_in[15];
  const float* w1 = (const float*)d_in[16];
  const float* b1 = (const float*)d_in[17];
  const float* w2 = (const float*)d_in[18];
  const float* b2 = (const float*)d_in[19];
  const float* fln_g = (const float*)d_in[20];
  const float* fln_b = (const float*)d_in[21];
  const float* out_g = (const float*)d_in[22];
  const float* out_b = (const float*)d_in[23];
  float* out = (float*)d_out;

  char* ws = (char*)d_ws;
  const size_t slotF = (size_t)RD * DM * 4;   // 16 MB
  const size_t slotB = (size_t)RD * DM * 2;   // 8 MB
  u16* wqkv_b = (u16*)(ws);                   // 9 x 1536 x 512 bf16 = 14155776
  u16* wo_b   = (u16*)(ws + 14155776);        // 4718592
  u16* w1_b   = (u16*)(ws + 18874368);        // 18874368
  u16* w2_b   = (u16*)(ws + 37748736);        // 18874368
  float* bqkv = (float*)(ws + 56623104);      // 55296
  const size_t oH = 56678400;
  float* Hs[3];  float* Acc[3];
  for (int j = 0; j < 3; ++j) Hs[j]  = (float*)(ws + oH + (size_t)j * slotF);
  for (int j = 0; j < 3; ++j) Acc[j] = out + (size_t)j * RD * DM;  // d_out as scratch
  float* pos = (float*)(ws + oH + 3 * slotF);            // 4 MB
  const size_t oL = oH + 3 * slotF + 4194304;            // 111204352
  const size_t laneSz = 5 * slotB;                       // 40 MB per lane
  int G = 1;
  if (ws_size >= oL + 3 * laneSz) G = 3;                 // 237 MB total
  else if (ws_size >= oL + 2 * laneSz) G = 2;

  // per-lane bf16 slots P0..P4:
  //   P0-2: PK packed QKV [8192][1536]     (dead after attn)
  //   P3:   XN x-LN out, then attn out     (dead after O-proj)
  //   P4:   KN ctx-LN out, then fLN out
  //   P0-1 (fp32 view): SOUT = x + attnO   (born at O-proj)
  //   P2-3: F1 half [8192][1024] bf16      (born at FFN1, reused both halves)
  auto PSLOT = [&](int j, int k) {
    return (u16*)(ws + oL + (size_t)j * laneSz + (size_t)k * slotB);
  };
  auto SOUT = [&](int j) { return (float*)PSLOT(j, 0); };

  // setup: weight packs, pos table, hidden init
  packqkv_k<<<dim3(3456), 256, 0, stream>>>(wq, wk, wv, wqkv_b);
  packbias_k<<<dim3(54), 256, 0, stream>>>(bq, bk, bv, bqkv);
  {
    CvtBatch cb{};
    cb.d[0] = CvtDesc{wo, wo_b, 294912};
    cb.d[1] = CvtDesc{w1, w1_b, 1179648};
    cb.d[2] = CvtDesc{w2, w2_b, 1179648};
    cvt_k<<<dim3(1024, 3), 256, 0, stream>>>(cb);
  }
  pos_k<<<dim3(4096), 256, 0, stream>>>(pos);
  hinit_k<<<dim3(4096, 3), 256, 0, stream>>>(initH, (float*)(ws + oH));

  // one branch chunk: LN(s) -> QKV -> attn -> O(+res) -> fLN -> 2x(FFN1h -> FFN2h)
  auto run_group = [&](int g, float* const* xv, float* const* ctx, const float* const* raw,
                       const int* wi, float* const* fout, int accum) {
    {
      LnBatch lb{}; int nd = 0;
      for (int j = 0; j < g; ++j)
        lb.d[nd++] = LnDesc{xv[j], nullptr, nullptr,
                            ln_g + wi[j] * DM, ln_b + wi[j] * DM, PSLOT(j, 3), nullptr};
      if (ctx || raw)
        for (int j = 0; j < g; ++j)
          lb.d[nd++] = LnDesc{ctx ? ctx[j] : nullptr, raw ? raw[j] : nullptr, pos,
                              lnkv_g + wi[j] * DM, lnkv_b + wi[j] * DM, PSLOT(j, 4), nullptr};
      ln_k<<<dim3(2048, nd), 256, 0, stream>>>(lb);
    }
    {
      GemmBatch gb{}; int nz = 0, gx;
      if (!ctx && !raw) {  // self: one fused N=1536 GEMM per branch
        for (int j = 0; j < g; ++j)
          gb.d[nz++] = GemmDesc{PSLOT(j, 3), wqkv_b + (size_t)wi[j] * 786432,
                                bqkv + wi[j] * 1536, nullptr, PSLOT(j, 0), nullptr,
                                512, 512, 12, 1536, 0, 0, 0};
        gx = 12;
      } else {             // cross: Q (N=512) + KV (N=1024) into the packed tensor
        for (int j = 0; j < g; ++j) {
          gb.d[nz++] = GemmDesc{PSLOT(j, 3), wqkv_b + (size_t)wi[j] * 786432,
                                bqkv + wi[j] * 1536, nullptr, PSLOT(j, 0), nullptr,
                                512, 512, 4, 1536, 0, 0, 0};
          gb.d[nz++] = GemmDesc{PSLOT(j, 4), wqkv_b + (size_t)wi[j] * 786432 + 262144,
                                bqkv + wi[j] * 1536 + 512, nullptr, PSLOT(j, 0), nullptr,
                                512, 512, 8, 1536, 512, 0, 0};
        }
        gx = 8;
      }
      gemm_k<128><<<dim3(gx, 64, nz), 256, 0, stream>>>(gb);
    }
    {
      AttnBatch ab{};
      for (int j = 0; j < g; ++j) ab.d[j] = AttnDesc{PSLOT(j, 0), PSLOT(j, 3)};
      attn_k<<<dim3(256, g), 256, 0, stream>>>(ab);
    }
    {
      GemmBatch gb{};
      for (int j = 0; j < g; ++j)
        gb.d[j] = GemmDesc{PSLOT(j, 3), wo_b + (size_t)wi[j] * DM * DM, bo + wi[j] * DM,
                           xv[j], nullptr, SOUT(j), 512, 512, 8, 512, 0, 0, 0};
      gemm_k<64><<<dim3(8, 64, g), 256, 0, stream>>>(gb);
    }
    {
      LnBatch lb{};
      for (int j = 0; j < g; ++j)
        lb.d[j] = LnDesc{SOUT(j), nullptr, nullptr,
                         fln_g + wi[j] * DM, fln_b + wi[j] * DM, PSLOT(j, 4), nullptr};
      ln_k<<<dim3(2048, g), 256, 0, stream>>>(lb);
    }
    for (int h = 0; h < 2; ++h) {
      {
        GemmBatch gb{};
        for (int j = 0; j < g; ++j)
          gb.d[j] = GemmDesc{PSLOT(j, 4), w1_b + (size_t)wi[j] * DF * DM + (size_t)h * 524288,
                             b1 + wi[j] * DF + h * 1024, nullptr, PSLOT(j, 2), nullptr,
                             512, 512, 8, 1024, 0, 1, 0};
        gemm_k<128><<<dim3(8, 64, g), 256, 0, stream>>>(gb);
      }
      {
        GemmBatch gb{};
        for (int j = 0; j < g; ++j)
          gb.d[j] = GemmDesc{PSLOT(j, 2), w2_b + (size_t)wi[j] * DM * DF + (size_t)h * 1024,
                             h == 0 ? b2 + wi[j] * DM : nullptr,
                             h == 0 ? SOUT(j) : nullptr, nullptr, fout[j],
                             1024, 2048, 8, 512, 0, 0, h == 0 ? accum : 1};
        gemm_k<64><<<dim3(8, 64, g), 256, 0, stream>>>(gb);
      }
    }
  };

  auto drive = [&](int n, float* const* xv, float* const* ctx, const float* const* raw,
                   const int* wi, float* const* fout, int accum) {
    for (int b = 0; b < n; b += G) {
      const int g = (G < n - b) ? G : n - b;
      run_group(g, xv + b, ctx ? ctx + b : nullptr, raw ? raw + b : nullptr,
                wi + b, fout + b, accum);
    }
  };

  // Stage A: hiddens cross-attend to embedded raw streams (embed fused into ctx-LN)
  {
    float* xv[3] = {Hs[0], Hs[1], Hs[2]};
    const float* raw[3] = {in_a, in_t, in_v};
    const int wi[3] = {0, 1, 2};
    float* fout[3] = {Hs[0], Hs[1], Hs[2]};
    drive(3, xv, nullptr, raw, wi, fout, 0);
  }
  // Stage B group 1: (at, tv, va) -> Acc[0..2]
  {
    float* xv[3] = {Hs[0], Hs[1], Hs[2]};
    float* ctx[3] = {Hs[1], Hs[2], Hs[0]};
    const int wi[3] = {3, 4, 5};
    float* fout[3] = {Acc[0], Acc[1], Acc[2]};
    drive(3, xv, ctx, nullptr, wi, fout, 0);
  }
  // Stage B group 2: (ta, vt, av) accumulate -> Acc[1], Acc[2], Acc[0]
  {
    float* xv[3] = {Hs[1], Hs[2], Hs[0]};
    float* ctx[3] = {Hs[0], Hs[1], Hs[2]};
    const int wi[3] = {3, 4, 5};
    float* fout[3] = {Acc[1], Acc[2], Acc[0]};
    drive(3, xv, ctx, nullptr, wi, fout, 1);
  }
  // Stage C: self-attention on combined hiddens -> Hs[0..2]
  {
    float* xv[3] = {Acc[0], Acc[1], Acc[2]};
    const int wi[3] = {6, 7, 8};
    float* fout[3] = {Hs[0], Hs[1], Hs[2]};
    drive(3, xv, nullptr, nullptr, wi, fout, 0);
  }
  // final LN -> d_out (3, SL, BS, D)  (Acc region dead by now)
  {
    LnBatch lb{};
    for (int j = 0; j < 3; ++j)
      lb.d[j] = LnDesc{Hs[j], nullptr, nullptr, out_g, out_b, nullptr,
                       out + (size_t)j * RD * DM};
    ln_k<<<dim3(2048, 3), 256, 0, stream>>>(lb);
  }
}